// Round 11
// baseline (335.587 us; speedup 1.0000x reference)
//
#include <hip/hip_runtime.h>
#include <hip/hip_cooperative_groups.h>

namespace cg = cooperative_groups;

// x: (2048, 200, 11, 11) f32.  NQUAD = 12,390,400 float4 quads.
// out = exp(-(x-center)^2/S - (|i-5|+|j-5|)/2),  S = global sum of (x-center)^2.
//
// R11: single cooperative kernel = proven R3 two-pass recompute (97.6 us,
// 6.09 TB/s on 594 MB = 97% of D2D ceiling) with the dispatch boundary
// replaced by grid.sync().  Phase bodies verbatim from the validated fb
// kernels.  Grid 1024x256 = 4 blocks/CU, LDS ~50 B, launch_bounds(256,4)
// caps VGPR at 128 (kernel needs ~45 -> no spill, co-residency guaranteed).
// Host fallback to the two-dispatch path if coop launch is rejected.

#define NQUAD    12390400
#define PLANE    121
#define CENTER   60
#define CBLK     1024
#define CTHR     256
#define FBBLK    2048
#define FBTHR    256
#define LOG2E    1.44269504088896340736f
#define NHALF_L2E (-0.72134752044448170368f)   // -0.5 * log2(e)

#if __has_builtin(__builtin_amdgcn_exp2f)
#define EXP2(v) __builtin_amdgcn_exp2f(v)
#else
#define EXP2(v) __expf((v) * 0.69314718055994530942f)
#endif

typedef float f32x4 __attribute__((ext_vector_type(4)));

// ------------------------- fused cooperative kernel -----------------------
__global__ __launch_bounds__(CTHR, 4) void fused_coop(
    const float* __restrict__ x, float* __restrict__ out,
    float* __restrict__ part)
{
    __shared__ float wsum[CTHR / 64];
    __shared__ float s_bcast;
    const int tid = threadIdx.x;

    // ---- phase A: S partials (verbatim fb_reduce body) ----
    float acc = 0.0f;
    for (int gq = blockIdx.x * CTHR + tid; gq < NQUAD; gq += CBLK * CTHR) {
        f32x4 v = reinterpret_cast<const f32x4*>(x)[gq];
        const int base = gq * 4;
        const int p0   = base / PLANE;            // magic-mul
        const int p3   = (base + 3) / PLANE;
        const int bnd  = (p0 + 1) * PLANE;
        const float cv0 = x[p0 * PLANE + CENTER];
        const float cv3 = x[p3 * PLANE + CENTER];
        float d0 = v[0] - cv0;
        float d1 = v[1] - ((base + 1 >= bnd) ? cv3 : cv0);
        float d2 = v[2] - ((base + 2 >= bnd) ? cv3 : cv0);
        float d3 = v[3] - ((base + 3 >= bnd) ? cv3 : cv0);
        acc += (d0*d0 + d1*d1) + (d2*d2 + d3*d3);
    }
    #pragma unroll
    for (int off = 32; off > 0; off >>= 1)
        acc += __shfl_down(acc, off, 64);
    if ((tid & 63) == 0) wsum[tid >> 6] = acc;
    __syncthreads();
    if (tid == 0)
        part[blockIdx.x] = wsum[0] + wsum[1] + wsum[2] + wsum[3];

    __threadfence();            // release partial (device scope)
    cg::this_grid().sync();
    __threadfence();            // acquire

    // ---- global sum of 1024 partials (every block, redundantly) ----
    float s = part[tid] + part[tid + 256] + part[tid + 512] + part[tid + 768];
    #pragma unroll
    for (int off = 32; off > 0; off >>= 1)
        s += __shfl_down(s, off, 64);
    __syncthreads();            // wsum reuse
    if ((tid & 63) == 0) wsum[tid >> 6] = s;
    __syncthreads();
    if (tid == 0)
        s_bcast = wsum[0] + wsum[1] + wsum[2] + wsum[3];
    __syncthreads();
    const float nInvSL2E = -LOG2E / s_bcast;

    // ---- phase B: emit (verbatim fb_finalize body) ----
    for (int gq = blockIdx.x * CTHR + tid; gq < NQUAD; gq += CBLK * CTHR) {
        f32x4 v = reinterpret_cast<const f32x4*>(x)[gq];
        const int base = gq * 4;
        const int p0   = base / PLANE;
        const int p3   = (base + 3) / PLANE;
        const int bnd  = (p0 + 1) * PLANE;
        const float cv0 = x[p0 * PLANE + CENTER];
        const float cv3 = x[p3 * PLANE + CENTER];
        f32x4 o;
        #pragma unroll
        for (int e = 0; e < 4; ++e) {
            int idx = base + e;
            int re  = idx - ((idx >= bnd) ? bnd : p0 * PLANE);
            int i   = re / 11;                    // magic-mul
            int j   = re - 11 * i;
            int di  = abs(i - 5) + abs(j - 5);
            float cv = (idx >= bnd) ? cv3 : cv0;
            float d  = v[e] - cv;
            o[e] = EXP2(fmaf(d * d, nInvSL2E, (float)di * NHALF_L2E));
        }
        reinterpret_cast<f32x4*>(out)[gq] = o;
    }
}

// ------------------ fallback: proven two-dispatch path --------------------
__global__ __launch_bounds__(FBTHR) void fb_reduce(
    const float* __restrict__ x, float* __restrict__ part)
{
    float acc = 0.0f;
    for (int gq = blockIdx.x * FBTHR + threadIdx.x; gq < NQUAD;
         gq += FBBLK * FBTHR) {
        f32x4 v = reinterpret_cast<const f32x4*>(x)[gq];
        const int base = gq * 4;
        const int p0   = base / PLANE;
        const int p3   = (base + 3) / PLANE;
        const int bnd  = (p0 + 1) * PLANE;
        const float cv0 = x[p0 * PLANE + CENTER];
        const float cv3 = x[p3 * PLANE + CENTER];
        float d0 = v[0] - cv0;
        float d1 = v[1] - ((base + 1 >= bnd) ? cv3 : cv0);
        float d2 = v[2] - ((base + 2 >= bnd) ? cv3 : cv0);
        float d3 = v[3] - ((base + 3 >= bnd) ? cv3 : cv0);
        acc += (d0*d0 + d1*d1) + (d2*d2 + d3*d3);
    }
    #pragma unroll
    for (int off = 32; off > 0; off >>= 1)
        acc += __shfl_down(acc, off, 64);
    __shared__ float wsum[FBTHR / 64];
    if ((threadIdx.x & 63) == 0) wsum[threadIdx.x >> 6] = acc;
    __syncthreads();
    if (threadIdx.x == 0)
        part[blockIdx.x] = wsum[0] + wsum[1] + wsum[2] + wsum[3];
}

__global__ __launch_bounds__(FBTHR) void fb_finalize(
    const float* __restrict__ x, const float* __restrict__ part,
    float* __restrict__ out)
{
    float s = 0.0f;
    for (int i = threadIdx.x; i < FBBLK; i += FBTHR)
        s += part[i];
    #pragma unroll
    for (int off = 32; off > 0; off >>= 1)
        s += __shfl_down(s, off, 64);
    __shared__ float wsum[FBTHR / 64];
    if ((threadIdx.x & 63) == 0) wsum[threadIdx.x >> 6] = s;
    __syncthreads();
    const float S = wsum[0] + wsum[1] + wsum[2] + wsum[3];
    const float nInvSL2E = -LOG2E / S;

    for (int gq = blockIdx.x * FBTHR + threadIdx.x; gq < NQUAD;
         gq += FBBLK * FBTHR) {
        f32x4 v = reinterpret_cast<const f32x4*>(x)[gq];
        const int base = gq * 4;
        const int p0   = base / PLANE;
        const int p3   = (base + 3) / PLANE;
        const int bnd  = (p0 + 1) * PLANE;
        const float cv0 = x[p0 * PLANE + CENTER];
        const float cv3 = x[p3 * PLANE + CENTER];
        f32x4 o;
        #pragma unroll
        for (int e = 0; e < 4; ++e) {
            int idx = base + e;
            int re  = idx - ((idx >= bnd) ? bnd : p0 * PLANE);
            int i   = re / 11;
            int j   = re - 11 * i;
            int di  = abs(i - 5) + abs(j - 5);
            float cv = (idx >= bnd) ? cv3 : cv0;
            float d  = v[e] - cv;
            o[e] = EXP2(fmaf(d * d, nInvSL2E, (float)di * NHALF_L2E));
        }
        reinterpret_cast<f32x4*>(out)[gq] = o;
    }
}

extern "C" void kernel_launch(void* const* d_in, const int* in_sizes, int n_in,
                              void* d_out, int out_size, void* d_ws, size_t ws_size,
                              hipStream_t stream)
{
    const float* x    = (const float*)d_in[0];
    float*       out  = (float*)d_out;
    float*       part = (float*)d_ws;   // up to 2048 floats, rewritten each call

    void* args[] = { (void*)&x, (void*)&out, (void*)&part };
    hipError_t err = hipLaunchCooperativeKernel(
        (const void*)fused_coop, dim3(CBLK), dim3(CTHR), args, 0, stream);
    if (err != hipSuccess) {
        // coop launch rejected -> proven two-dispatch path (97.6 us)
        fb_reduce<<<FBBLK, FBTHR, 0, stream>>>(x, part);
        fb_finalize<<<FBBLK, FBTHR, 0, stream>>>(x, part, out);
    }
}